// Round 1
// baseline (74.281 us; speedup 1.0000x reference)
//
#include <hip/hip_runtime.h>
#include <cstdint>

#define PEDS   64
#define HIDDEN 128
#define POOL   64
#define GRIDG  4
#define NBHD   2.0f

typedef unsigned short u16;
typedef unsigned int   u32;
typedef __attribute__((ext_vector_type(8))) short bf16x8;
typedef __attribute__((ext_vector_type(4))) float f32x4;

__device__ __forceinline__ u16 f2bf(float f) {
    u32 u = __float_as_uint(f);
    u += 0x7fffu + ((u >> 16) & 1u);   // RNE
    return (u16)(u >> 16);
}
__device__ __forceinline__ u32 pack2bf(float a, float b) {
    return (u32)f2bf(a) | ((u32)f2bf(b) << 16);
}

// Column-split: grid = 2*B. Block = (scene s = blockIdx>>1, col-half nh = blockIdx&1).
// 256 threads = 4 waves; wave wv owns m-tile mt=wv (16 rows) x 32 cols (this block's half).
// 2 blocks/CU (44KB LDS each) -> independent barrier domains hide each other's stalls.
// out = sum_g M_g @ (h @ W_g), both matmuls MFMA; same math/order as 1-block version.
// LDS 44KB: gidx[64x64] 4K | wmask | hA bf16[64][128] 16K |
//           wS bf16[2][32][128] 16K | hwT bf16[32][64] 4K
__global__ __launch_bounds__(256, 2) void social_fused(
    const float* __restrict__ h, const float* __restrict__ pos,
    const float* __restrict__ w, const float* __restrict__ bias,
    float* __restrict__ out)
{
    __shared__ unsigned char LB[45056];
    unsigned char* gidx  = LB;                    // [0, 4096)
    u32*           wmask = (u32*)(LB + 4096);     // 4 words
    u16*           hA    = (u16*)(LB + 8192);     // [8192, 24576)
    u16*           hwT   = (u16*)(LB + 40960);    // [40960, 45056)

    const int s    = blockIdx.x >> 1;
    const int nh   = blockIdx.x & 1;
    const int tid  = threadIdx.x;
    const int wv   = tid >> 6;        // 0..3
    const int lane = tid & 63;
    const int l15  = lane & 15;
    const int q    = lane >> 4;
    const int mt   = wv;              // m-tile = wave

    // positions: each wave's lane l holds ped l
    float2 pp = ((const float2*)pos)[(size_t)s * PEDS + lane];
    float px = pp.x, py = pp.y;

    // h load: row = tid>>2, 32 floats at (tid&3)*32
    const int hrow = tid >> 2, hc = tid & 3;
    const float4* hsrc = (const float4*)(h + ((size_t)s * PEDS + hrow) * HIDDEN + hc * 32);
    float4 hv[8];
#pragma unroll
    for (int i = 0; i < 8; ++i) hv[i] = hsrc[i];

    // gidx: i = wv*16 + (lane>>2); j = (lane&3)*16 + u  (16 j's per lane)
    const int gi  = wv * 16 + (lane >> 2);
    const int gj0 = (lane & 3) * 16;
    const float pxi = __shfl(px, gi), pyi = __shfl(py, gi);
    u32 gpk[4] = {0u, 0u, 0u, 0u};
    u32 um = 0;
    const float scale = (float)GRIDG / (2.0f * NBHD);
#pragma unroll
    for (int u8 = 0; u8 < 16; ++u8) {
        int j = gj0 + u8;
        float rx = __shfl(px, j) - pxi;
        float ry = __shfl(py, j) - pyi;
        u32 gb = 0xffu;
        if ((gi != j) && (fabsf(rx) <= NBHD) && (fabsf(ry) <= NBHD)) {
            int gx = (int)floorf((rx + NBHD) * scale); gx = min(max(gx, 0), GRIDG - 1);
            int gy = (int)floorf((ry + NBHD) * scale); gy = min(max(gy, 0), GRIDG - 1);
            int g = gy * GRIDG + gx;
            gb = (u32)g; um |= 1u << g;
        }
        gpk[u8 >> 2] |= gb << ((u8 & 3) * 8);
    }
    *(uint4*)&gidx[gi * 64 + gj0] = make_uint4(gpk[0], gpk[1], gpk[2], gpk[3]);

    // per-wave OR-reduce of used-cell mask
#pragma unroll
    for (int off = 32; off; off >>= 1) um |= __shfl_xor(um, off);
    if (lane == 0) wmask[wv] = um;

    // hA: bf16 convert, chunk ch stored at ch ^ (row&15)
#pragma unroll
    for (int k2 = 0; k2 < 4; ++k2) {
        u32 p0 = pack2bf(hv[2 * k2].x, hv[2 * k2].y);
        u32 p1 = pack2bf(hv[2 * k2].z, hv[2 * k2].w);
        u32 p2 = pack2bf(hv[2 * k2 + 1].x, hv[2 * k2 + 1].y);
        u32 p3 = pack2bf(hv[2 * k2 + 1].z, hv[2 * k2 + 1].w);
        int ch = hc * 4 + k2;
        *(uint4*)&hA[hrow * 128 + ((ch ^ (hrow & 15)) << 3)] = make_uint4(p0, p1, p2, p3);
    }
    __syncthreads();                               // B1: gidx, wmask, hA visible

    u32 mask = wmask[0] | wmask[1] | wmask[2] | wmask[3];
    mask = __builtin_amdgcn_readfirstlane(mask);

    // A fragments (h rows of this wave's m-tile) -> registers; hA dead after
    bf16x8 af[4];
#pragma unroll
    for (int st4 = 0; st4 < 4; ++st4)
        af[st4] = *(const bf16x8*)&hA[(mt * 16 + l15) * 128 + (((st4 * 4 + q) ^ l15) << 3)];

    const int ng = __popc(mask);
    u32 rem = mask;
    int g = 0;
    if (rem) { g = __ffs(rem) - 1; rem &= rem - 1u; }

    // W prefetch: this block's 32 cols. c = nh*32 + (lane&31), k = wv*32 + (lane>>5)*16 + e
    float wr[16];
    const int wc = lane & 31;
    const int wk = wv * 32 + (lane >> 5) * 16;
    if (ng) {
        const float* wsrc = w + ((size_t)g * HIDDEN + wk) * POOL + nh * 32 + wc;
#pragma unroll
        for (int e = 0; e < 16; ++e) wr[e] = wsrc[(size_t)e * POOL];
    }

    f32x4 oacc[2];
    oacc[0] = (f32x4){0.f, 0.f, 0.f, 0.f};
    oacc[1] = (f32x4){0.f, 0.f, 0.f, 0.f};

    for (int t = 0; t < ng; ++t) {
        u16* wSb = (u16*)(LB + 24576 + ((t & 1) << 13));   // 8KB double buffers
        // stage current W from registers (swizzled): [32 c][128 k] bf16
#pragma unroll
        for (int cc = 0; cc < 2; ++cc) {
            u32 p0 = pack2bf(wr[cc * 8 + 0], wr[cc * 8 + 1]);
            u32 p1 = pack2bf(wr[cc * 8 + 2], wr[cc * 8 + 3]);
            u32 p2 = pack2bf(wr[cc * 8 + 4], wr[cc * 8 + 5]);
            u32 p3 = pack2bf(wr[cc * 8 + 6], wr[cc * 8 + 7]);
            int ch = (wk >> 3) + cc;                       // wv*4 + (lane>>5)*2 + cc
            *(uint4*)&wSb[wc * 128 + ((ch ^ (wc & 15)) << 3)] = make_uint4(p0, p1, p2, p3);
        }
        // prefetch next cell's W (hidden under GEMMs)
        int gn = -1;
        if (rem) { gn = __ffs(rem) - 1; rem &= rem - 1u; }
        if (gn >= 0) {
            const float* wsrc = w + ((size_t)gn * HIDDEN + wk) * POOL + nh * 32 + wc;
#pragma unroll
            for (int e = 0; e < 16; ++e) wr[e] = wsrc[(size_t)e * POOL];
        }
        __syncthreads();      // A: wS[t&1] staged; all waves done with GEMM2(t-1)

        // GEMM1: hw_g[j,c] = h[j,:].W_g[:,c]; this wave: 16 j x 32 c
        f32x4 a1[2];
        a1[0] = (f32x4){0.f, 0.f, 0.f, 0.f};
        a1[1] = (f32x4){0.f, 0.f, 0.f, 0.f};
#pragma unroll
        for (int st4 = 0; st4 < 4; ++st4) {
            int chs = ((st4 * 4 + q) ^ l15) << 3;
            bf16x8 b0 = *(const bf16x8*)&wSb[(l15) * 128 + chs];
            bf16x8 b1 = *(const bf16x8*)&wSb[(16 + l15) * 128 + chs];
            a1[0] = __builtin_amdgcn_mfma_f32_16x16x32_bf16(af[st4], b0, a1[0], 0, 0, 0);
            a1[1] = __builtin_amdgcn_mfma_f32_16x16x32_bf16(af[st4], b1, a1[1], 0, 0, 0);
        }
        // hwT[c][j] bf16 (c local 0..31), j-quad jq stored at jq ^ (c&15)
#pragma unroll
        for (int ni = 0; ni < 2; ++ni) {
            int c = ni * 16 + l15;
            u32 lo = pack2bf(a1[ni][0], a1[ni][1]);
            u32 hi = pack2bf(a1[ni][2], a1[ni][3]);
            *(uint2*)&hwT[c * 64 + (((mt * 4 + q) ^ (c & 15)) << 2)] = make_uint2(lo, hi);
        }
        __syncthreads();      // B: hwT visible

        // GEMM2: oacc += M_g @ hw_g   (K=64, 2 k-steps)
#pragma unroll
        for (int kk = 0; kk < 2; ++kk) {
            uint2 gg = *(const uint2*)&gidx[(mt * 16 + l15) * 64 + kk * 32 + q * 8];
            union { u16 hx[8]; bf16x8 v; } mu;
#pragma unroll
            for (int b = 0; b < 4; ++b)
                mu.hx[b]     = (((gg.x >> (b * 8)) & 0xffu) == (u32)g) ? (u16)0x3F80 : (u16)0;
#pragma unroll
            for (int b = 0; b < 4; ++b)
                mu.hx[4 + b] = (((gg.y >> (b * 8)) & 0xffu) == (u32)g) ? (u16)0x3F80 : (u16)0;
#pragma unroll
            for (int ni = 0; ni < 2; ++ni) {
                int c = ni * 16 + l15;
                int cs = c & 15;
                uint2 b0 = *(const uint2*)&hwT[c * 64 + (((kk * 8 + q * 2 + 0) ^ cs) << 2)];
                uint2 b1 = *(const uint2*)&hwT[c * 64 + (((kk * 8 + q * 2 + 1) ^ cs) << 2)];
                union { u32 u[4]; bf16x8 v; } bu;
                bu.u[0] = b0.x; bu.u[1] = b0.y; bu.u[2] = b1.x; bu.u[3] = b1.y;
                oacc[ni] = __builtin_amdgcn_mfma_f32_16x16x32_bf16(mu.v, bu.v, oacc[ni], 0, 0, 0);
            }
        }
        g = gn;
    }

    // epilogue: out[i,c] = oacc + bias; i = mt*16+q*4+r, c = nh*32+ni*16+l15
#pragma unroll
    for (int ni = 0; ni < 2; ++ni) {
        int c = nh * 32 + ni * 16 + l15;
        float bv = bias[c];
        size_t ob = ((size_t)s * PEDS + mt * 16 + q * 4) * POOL + c;
#pragma unroll
        for (int r = 0; r < 4; ++r)
            out[ob + (size_t)r * POOL] = oacc[ni][r] + bv;
    }
}

extern "C" void kernel_launch(void* const* d_in, const int* in_sizes, int n_in,
                              void* d_out, int out_size, void* d_ws, size_t ws_size,
                              hipStream_t stream) {
    const float* h    = (const float*)d_in[0];
    const float* pos  = (const float*)d_in[1];
    const float* w    = (const float*)d_in[2];
    const float* bias = (const float*)d_in[3];
    float* out = (float*)d_out;

    const int total = in_sizes[0] / HIDDEN;
    const int B     = total / PEDS;

    hipLaunchKernelGGL(social_fused, dim3(B * 2), dim3(256), 0, stream,
                       h, pos, w, bias, out);
}

// Round 2
// 71.125 us; speedup vs baseline: 1.0444x; 1.0444x over previous
//
#include <hip/hip_runtime.h>
#include <cstdint>

#define PEDS   64
#define HIDDEN 128
#define POOL   64
#define GRIDG  4
#define NBHD   2.0f

typedef unsigned short u16;
typedef unsigned int   u32;
typedef __attribute__((ext_vector_type(8))) short bf16x8;
typedef __attribute__((ext_vector_type(4))) float f32x4;

__device__ __forceinline__ u16 f2bf(float f) {
    u32 u = __float_as_uint(f);
    u += 0x7fffu + ((u >> 16) & 1u);   // RNE
    return (u16)(u >> 16);
}
__device__ __forceinline__ u32 pack2bf(float a, float b) {
    return (u32)f2bf(a) | ((u32)f2bf(b) << 16);
}

// One block per scene, 512 threads (8 waves). Wave wv: m-tile mt=wv&3, n-half nh=wv>>2.
// Flattened schedule: 3 barriers TOTAL for the common ng<=4 case (vs 2+2*ng before):
//   setup(gidx,hA) -B1- stage W for ALL used cells -B2- GEMM1 x cells -> hwT -B3-
//   batched GEMM2 (K = ng*64) -> epilogue.
// LDS 104KB: gidx[64x64] 4K | wmask | hA bf16[64][128] 16K @8192 |
//            hwT bf16[64][256] 32K @8192 (ALIASES hA: af regs loaded before B2,
//            first hwT write after B2 -> race-free) | wS bf16[4][64][128] 64K @40960
__global__ __launch_bounds__(512) void social_fused(
    const float* __restrict__ h, const float* __restrict__ pos,
    const float* __restrict__ w, const float* __restrict__ bias,
    float* __restrict__ out)
{
    __shared__ unsigned char LB[106496];
    unsigned char* gidx  = LB;                    // [0, 4096)
    u32*           wmask = (u32*)(LB + 4096);     // 8 words
    u16*           hA    = (u16*)(LB + 8192);     // [8192, 24576)
    u16*           hwT   = (u16*)(LB + 8192);     // [8192, 40960)  (aliases hA)
    u16*           wS    = (u16*)(LB + 40960);    // [40960, 106496)

    const int s    = blockIdx.x;
    const int tid  = threadIdx.x;
    const int wv   = tid >> 6;
    const int lane = tid & 63;
    const int l15  = lane & 15;
    const int q    = lane >> 4;
    const int mt   = wv & 3;
    const int nh   = wv >> 2;

    // positions: each wave's lane l holds ped l
    float2 pp = ((const float2*)pos)[(size_t)s * PEDS + lane];
    float px = pp.x, py = pp.y;

    // h load: row = tid>>3, 16 floats at (tid&7)*16
    const int hrow = tid >> 3, hc = tid & 7;
    const float4* hsrc = (const float4*)(h + ((size_t)s * PEDS + hrow) * HIDDEN + hc * 16);
    float4 hv0 = hsrc[0], hv1 = hsrc[1], hv2 = hsrc[2], hv3 = hsrc[3];

    // gidx: i = wv*8 + (lane>>3); j = (lane&7)*8 + u
    const int gi  = wv * 8 + (lane >> 3);
    const int gj0 = (lane & 7) * 8;
    const float pxi = __shfl(px, gi), pyi = __shfl(py, gi);
    u32 gpk0 = 0, gpk1 = 0, um = 0;
    const float scale = (float)GRIDG / (2.0f * NBHD);
#pragma unroll
    for (int u8 = 0; u8 < 8; ++u8) {
        int j = gj0 + u8;
        float rx = __shfl(px, j) - pxi;
        float ry = __shfl(py, j) - pyi;
        u32 gb = 0xffu;
        if ((gi != j) && (fabsf(rx) <= NBHD) && (fabsf(ry) <= NBHD)) {
            int gx = (int)floorf((rx + NBHD) * scale); gx = min(max(gx, 0), GRIDG - 1);
            int gy = (int)floorf((ry + NBHD) * scale); gy = min(max(gy, 0), GRIDG - 1);
            int g = gy * GRIDG + gx;
            gb = (u32)g; um |= 1u << g;
        }
        if (u8 < 4) gpk0 |= gb << (u8 * 8); else gpk1 |= gb << ((u8 - 4) * 8);
    }
    *(uint2*)&gidx[gi * 64 + gj0] = make_uint2(gpk0, gpk1);

    // per-wave OR-reduce of used-cell mask
#pragma unroll
    for (int off = 32; off; off >>= 1) um |= __shfl_xor(um, off);
    if (lane == 0) wmask[wv] = um;

    // hA: bf16 convert, chunk c stored at c ^ (row&15)
    {
        u32 p0 = pack2bf(hv0.x, hv0.y), p1 = pack2bf(hv0.z, hv0.w);
        u32 p2 = pack2bf(hv1.x, hv1.y), p3 = pack2bf(hv1.z, hv1.w);
        int ch = hc * 2;
        *(uint4*)&hA[hrow * 128 + ((ch ^ (hrow & 15)) << 3)] = make_uint4(p0, p1, p2, p3);
        p0 = pack2bf(hv2.x, hv2.y); p1 = pack2bf(hv2.z, hv2.w);
        p2 = pack2bf(hv3.x, hv3.y); p3 = pack2bf(hv3.z, hv3.w);
        ch = hc * 2 + 1;
        *(uint4*)&hA[hrow * 128 + ((ch ^ (hrow & 15)) << 3)] = make_uint4(p0, p1, p2, p3);
    }
    __syncthreads();                               // B1: gidx, wmask, hA visible

    u32 mask = wmask[0] | wmask[1] | wmask[2] | wmask[3]
             | wmask[4] | wmask[5] | wmask[6] | wmask[7];
    mask = __builtin_amdgcn_readfirstlane(mask);

    // A fragments -> registers (hA dead afterwards; B2 orders these reads
    // against the hwT writes that alias hA)
    bf16x8 af[4];
#pragma unroll
    for (int st4 = 0; st4 < 4; ++st4)
        af[st4] = *(const bf16x8*)&hA[(mt * 16 + l15) * 128 + (((st4 * 4 + q) ^ l15) << 3)];

    f32x4 oacc[2];
    oacc[0] = (f32x4){0.f, 0.f, 0.f, 0.f};
    oacc[1] = (f32x4){0.f, 0.f, 0.f, 0.f};

    u32 rem = mask;
    const int wc = lane, wk = wv * 16;

    while (rem) {      // one pass per <=4 used cells; typically exactly one pass
        int cg0, cg1 = -1, cg2 = -1, cg3 = -1;
        cg0 = __ffs(rem) - 1; rem &= rem - 1u;
        if (rem) { cg1 = __ffs(rem) - 1; rem &= rem - 1u;
            if (rem) { cg2 = __ffs(rem) - 1; rem &= rem - 1u;
                if (rem) { cg3 = __ffs(rem) - 1; rem &= rem - 1u; } } }

        // ---- stage W for all cells of this pass (no barriers between) ----
#define STAGE_CELL(T, CG) if ((CG) >= 0) { \
        const float* wsrc = w + ((size_t)(CG) * HIDDEN + wk) * POOL + wc; \
        float wr[16]; \
        _Pragma("unroll") for (int e = 0; e < 16; ++e) wr[e] = wsrc[(size_t)e * POOL]; \
        u16* wSb = wS + (T) * 8192; \
        _Pragma("unroll") for (int cc = 0; cc < 2; ++cc) { \
            u32 p0 = pack2bf(wr[cc*8+0], wr[cc*8+1]); \
            u32 p1 = pack2bf(wr[cc*8+2], wr[cc*8+3]); \
            u32 p2 = pack2bf(wr[cc*8+4], wr[cc*8+5]); \
            u32 p3 = pack2bf(wr[cc*8+6], wr[cc*8+7]); \
            int ch = wv * 2 + cc; \
            *(uint4*)&wSb[wc * 128 + ((ch ^ (wc & 15)) << 3)] = make_uint4(p0, p1, p2, p3); \
        } }

        STAGE_CELL(0, cg0)
        STAGE_CELL(1, cg1)
        STAGE_CELL(2, cg2)
        STAGE_CELL(3, cg3)

        __syncthreads();   // B2: wS staged for all cells; GEMM2(prev pass) done

        // ---- GEMM1 for all cells, back-to-back (pure LDS->MFMA pipeline) ----
#define GEMM1_CELL(T, CG) if ((CG) >= 0) { \
        const u16* wSb = wS + (T) * 8192; \
        f32x4 a10 = (f32x4){0.f,0.f,0.f,0.f}, a11 = (f32x4){0.f,0.f,0.f,0.f}; \
        _Pragma("unroll") for (int st4 = 0; st4 < 4; ++st4) { \
            int chs = ((st4 * 4 + q) ^ l15) << 3; \
            bf16x8 b0 = *(const bf16x8*)&wSb[(nh * 32 + l15) * 128 + chs]; \
            bf16x8 b1 = *(const bf16x8*)&wSb[(nh * 32 + 16 + l15) * 128 + chs]; \
            a10 = __builtin_amdgcn_mfma_f32_16x16x32_bf16(af[st4], b0, a10, 0, 0, 0); \
            a11 = __builtin_amdgcn_mfma_f32_16x16x32_bf16(af[st4], b1, a11, 0, 0, 0); \
        } \
        { int c = nh * 32 + l15; int cs = c & 15; \
          *(uint2*)&hwT[c * 256 + (T) * 64 + (((mt * 4 + q) ^ cs) << 2)] = \
              make_uint2(pack2bf(a10[0], a10[1]), pack2bf(a10[2], a10[3])); } \
        { int c = nh * 32 + 16 + l15; int cs = c & 15; \
          *(uint2*)&hwT[c * 256 + (T) * 64 + (((mt * 4 + q) ^ cs) << 2)] = \
              make_uint2(pack2bf(a11[0], a11[1]), pack2bf(a11[2], a11[3])); } }

        GEMM1_CELL(0, cg0)
        GEMM1_CELL(1, cg1)
        GEMM1_CELL(2, cg2)
        GEMM1_CELL(3, cg3)

        __syncthreads();   // B3: hwT visible

        // ---- batched GEMM2: oacc += sum_t M_{g_t} @ hw_{g_t}  (K = nc*64) ----
#pragma unroll
        for (int kk = 0; kk < 2; ++kk) {
            uint2 gg = *(const uint2*)&gidx[(mt * 16 + l15) * 64 + kk * 32 + q * 8];

#define GEMM2_CELL(T, CG) if ((CG) >= 0) { \
            union { u16 hx[8]; bf16x8 v; } mu; \
            _Pragma("unroll") for (int b = 0; b < 4; ++b) \
                mu.hx[b]     = (((gg.x >> (b * 8)) & 0xffu) == (u32)(CG)) ? (u16)0x3F80 : (u16)0; \
            _Pragma("unroll") for (int b = 0; b < 4; ++b) \
                mu.hx[4 + b] = (((gg.y >> (b * 8)) & 0xffu) == (u32)(CG)) ? (u16)0x3F80 : (u16)0; \
            _Pragma("unroll") for (int ni = 0; ni < 2; ++ni) { \
                int c = nh * 32 + ni * 16 + l15; int cs = c & 15; \
                uint2 b0 = *(const uint2*)&hwT[c * 256 + (T) * 64 + (((kk * 8 + q * 2 + 0) ^ cs) << 2)]; \
                uint2 b1 = *(const uint2*)&hwT[c * 256 + (T) * 64 + (((kk * 8 + q * 2 + 1) ^ cs) << 2)]; \
                union { u32 u[4]; bf16x8 v; } bu; \
                bu.u[0] = b0.x; bu.u[1] = b0.y; bu.u[2] = b1.x; bu.u[3] = b1.y; \
                oacc[ni] = __builtin_amdgcn_mfma_f32_16x16x32_bf16(mu.v, bu.v, oacc[ni], 0, 0, 0); \
            } }

            GEMM2_CELL(0, cg0)
            GEMM2_CELL(1, cg1)
            GEMM2_CELL(2, cg2)
            GEMM2_CELL(3, cg3)
        }
        // next pass (rare, ng>4): staging writes wS only after all waves passed B3,
        // and GEMM1(p+1) writes hwT only after B2(p+1) (all waves done with GEMM2(p)).
    }

    // epilogue: out[i,c] = oacc + bias; i = mt*16+q*4+r, c = nh*32+ni*16+l15
#pragma unroll
    for (int ni = 0; ni < 2; ++ni) {
        int c = nh * 32 + ni * 16 + l15;
        float bv = bias[c];
        size_t ob = ((size_t)s * PEDS + mt * 16 + q * 4) * POOL + c;
#pragma unroll
        for (int r = 0; r < 4; ++r)
            out[ob + (size_t)r * POOL] = oacc[ni][r] + bv;
    }
}

extern "C" void kernel_launch(void* const* d_in, const int* in_sizes, int n_in,
                              void* d_out, int out_size, void* d_ws, size_t ws_size,
                              hipStream_t stream) {
    const float* h    = (const float*)d_in[0];
    const float* pos  = (const float*)d_in[1];
    const float* w    = (const float*)d_in[2];
    const float* bias = (const float*)d_in[3];
    float* out = (float*)d_out;

    const int total = in_sizes[0] / HIDDEN;
    const int B     = total / PEDS;

    hipLaunchKernelGGL(social_fused, dim3(B), dim3(512), 0, stream,
                       h, pos, w, bias, out);
}